// Round 5
// baseline (2102.515 us; speedup 1.0000x reference)
//
#include <hip/hip_runtime.h>
#include <cstdint>

// ---------------------------------------------------------------------------
// EETransformerEncoder on MI355X (gfx950).  Round 5.
// - K=256 GEMMs (QKV/Wo/FF1): full-K LDS-resident, ONE barrier per kernel.
//   QKV/FF1 fuse LayerNorm into A-staging (read x directly; y removed).
//   Wo fuses attention split-combine into A-staging and does x+=C+bo epilogue.
// - FF2: split-K=2 with atomicAdd epilogue into x (+b2 at z==0) - no combine.
// - prep consolidated to one kernel. 5 dispatches/layer, 87 total.
// ---------------------------------------------------------------------------

typedef __bf16 bf16_t;
typedef bf16_t bf16x4 __attribute__((ext_vector_type(4)));
typedef bf16_t bf16x8 __attribute__((ext_vector_type(8)));
typedef float  f32x4  __attribute__((ext_vector_type(4)));

#define B_    8
#define T_    512
#define IDIM  1799
#define KPAD  1856        // 29*64
#define D_    256
#define H_    4
#define DK    64
#define FF_   2048
#define L_    16
#define NROW  4096        // B_*T_
#define PKROWS 2000       // 2*MAXLEN
#define NBH   32          // B_*H_
#define NSA   4           // attention s-splits

__device__ __forceinline__ f32x4 mfma16(bf16x8 a, bf16x8 b, f32x4 c) {
  return __builtin_amdgcn_mfma_f32_16x16x32_bf16(a, b, c, 0, 0, 0);
}

__device__ __forceinline__ void async_cp16(const void* g, void* l) {
  __builtin_amdgcn_global_load_lds(
      (__attribute__((address_space(1))) void*)(g),
      (__attribute__((address_space(3))) void*)(l), 16, 0, 0);
}

// ---------------------------------------------------------------------------
// prep: all weight conversions/packing in one grid-stride kernel
// ---------------------------------------------------------------------------
#define WCAT_N (L_ * 768 * 256)
#define WOB_N  (L_ * 256 * 256)
#define W1B_N  (L_ * 2048 * 256)
#define W2B_N  (L_ * 256 * 2048)
#define BCAT_N (L_ * 768)
#define PREP_TOT (WCAT_N + WOB_N + W1B_N + W2B_N + BCAT_N)

__global__ __launch_bounds__(256) void prep_all(
    const float* __restrict__ wq, const float* __restrict__ wk,
    const float* __restrict__ wv, const float* __restrict__ wo,
    const float* __restrict__ w1, const float* __restrict__ w2,
    const float* __restrict__ bq, const float* __restrict__ bk,
    const float* __restrict__ bv, bf16_t* __restrict__ wcat,
    bf16_t* __restrict__ wob, bf16_t* __restrict__ w1b,
    bf16_t* __restrict__ w2b, float* __restrict__ bcat) {
  const int stride = gridDim.x * 256;
  for (int i = blockIdx.x * 256 + threadIdx.x; i < PREP_TOT; i += stride) {
    int j = i;
    if (j < WCAT_N) {
      const int per_l = 768 * 256;
      int l = j / per_l, r = j - l * per_l;
      int n = r >> 8, c = r & 255;
      int sel = n >> 8, nn = n & 255;
      const float* wsrc = (sel == 0) ? wq : (sel == 1) ? wk : wv;
      wcat[j] = (bf16_t)wsrc[((size_t)l * 256 + nn) * 256 + c];
      continue;
    }
    j -= WCAT_N;
    if (j < WOB_N) { wob[j] = (bf16_t)wo[j]; continue; }
    j -= WOB_N;
    if (j < W1B_N) { w1b[j] = (bf16_t)w1[j]; continue; }
    j -= W1B_N;
    if (j < W2B_N) { w2b[j] = (bf16_t)w2[j]; continue; }
    j -= W2B_N;
    {
      int l = j / 768, n = j - l * 768;
      int sel = n >> 8, nn = n & 255;
      const float* bsrc = (sel == 0) ? bq : (sel == 1) ? bk : bv;
      bcat[j] = bsrc[l * 256 + nn];
    }
  }
}

__global__ __launch_bounds__(256) void cvt_pad_row(const float* __restrict__ s,
                                                   bf16_t* __restrict__ d,
                                                   int ksrc, int kdst) {
  const int r = blockIdx.x;
  const float* sr = s + (size_t)r * ksrc;
  bf16_t* dr = d + (size_t)r * kdst;
  for (int k = threadIdx.x; k < kdst; k += 256)
    dr[k] = (k < ksrc) ? (bf16_t)sr[k] : (bf16_t)0.f;
}

__global__ __launch_bounds__(256) void pkn_ln(const float* __restrict__ pe_k,
                                              const float* __restrict__ lnk_g,
                                              const float* __restrict__ lnk_b,
                                              bf16_t* __restrict__ out) {
  const int idx = blockIdx.x * 4 + (threadIdx.x >> 6);
  if (idx >= L_ * PKROWS) return;
  const int lane = threadIdx.x & 63;
  const int l = idx / PKROWS, r = idx - l * PKROWS;
  float v = pe_k[(size_t)r * DK + lane];
  float s = v;
#pragma unroll
  for (int o = 32; o; o >>= 1) s += __shfl_xor(s, o);
  const float mean = s * (1.f / DK);
  const float dx = v - mean;
  float q = dx * dx;
#pragma unroll
  for (int o = 32; o; o >>= 1) q += __shfl_xor(q, o);
  const float rs = rsqrtf(q * (1.f / DK) + 1e-12f);
  out[((size_t)l * PKROWS + r) * DK + lane] =
      (bf16_t)(dx * rs * lnk_g[l * DK + lane] + lnk_b[l * DK + lane]);
}

// ---------------------------------------------------------------------------
// final LayerNorm (fp32 out), one wave per row
// ---------------------------------------------------------------------------
__global__ __launch_bounds__(256) void ln_rows_f32(const float* __restrict__ src,
                                                   const float* __restrict__ g,
                                                   const float* __restrict__ b,
                                                   float* __restrict__ dst) {
  const int row = blockIdx.x * 4 + (threadIdx.x >> 6);
  const int lane = threadIdx.x & 63;
  const float4 v = ((const float4*)(src + (size_t)row * D_))[lane];
  float s = v.x + v.y + v.z + v.w;
#pragma unroll
  for (int o = 32; o; o >>= 1) s += __shfl_xor(s, o);
  const float mean = s * (1.f / D_);
  const float d0 = v.x - mean, d1 = v.y - mean, d2 = v.z - mean, d3 = v.w - mean;
  float q = d0 * d0 + d1 * d1 + d2 * d2 + d3 * d3;
#pragma unroll
  for (int o = 32; o; o >>= 1) q += __shfl_xor(q, o);
  const float rs = rsqrtf(q * (1.f / D_) + 1e-12f);
  const float4 gg = ((const float4*)g)[lane];
  const float4 bb = ((const float4*)b)[lane];
  ((float4*)(dst + (size_t)row * D_))[lane] =
      make_float4(d0 * rs * gg.x + bb.x, d1 * rs * gg.y + bb.y,
                  d2 * rs * gg.z + bb.z, d3 * rs * gg.w + bb.w);
}

// embed combine: x = relu(LN(sum4(parts)+bias))
__global__ __launch_bounds__(256) void embed_combine(
    const float* __restrict__ parts, const float* __restrict__ bias,
    const float* __restrict__ g0, const float* __restrict__ b0,
    float* __restrict__ x) {
  const int row = blockIdx.x * 4 + (threadIdx.x >> 6);
  const int lane = threadIdx.x & 63;
  const size_t idx = (size_t)row * 64 + lane;
  float4 v = ((const float4*)parts)[idx];
#pragma unroll
  for (int p = 1; p < 4; ++p) {
    float4 pv = ((const float4*)parts)[(size_t)p * NROW * 64 + idx];
    v.x += pv.x; v.y += pv.y; v.z += pv.z; v.w += pv.w;
  }
  const float4 bi = ((const float4*)bias)[lane];
  v.x += bi.x; v.y += bi.y; v.z += bi.z; v.w += bi.w;
  float s = v.x + v.y + v.z + v.w;
#pragma unroll
  for (int o = 32; o; o >>= 1) s += __shfl_xor(s, o);
  const float mean = s * (1.f / D_);
  const float d0 = v.x - mean, d1 = v.y - mean, d2 = v.z - mean, d3 = v.w - mean;
  float q = d0 * d0 + d1 * d1 + d2 * d2 + d3 * d3;
#pragma unroll
  for (int o = 32; o; o >>= 1) q += __shfl_xor(q, o);
  const float rs = rsqrtf(q * (1.f / D_) + 1e-12f);
  const float4 gg = ((const float4*)g0)[lane];
  const float4 bb = ((const float4*)b0)[lane];
  ((float4*)x)[idx] = make_float4(
      fmaxf(d0 * rs * gg.x + bb.x, 0.f), fmaxf(d1 * rs * gg.y + bb.y, 0.f),
      fmaxf(d2 * rs * gg.z + bb.z, 0.f), fmaxf(d3 * rs * gg.w + bb.w, 0.f));
}

// ---------------------------------------------------------------------------
// embed GEMM (split-K to f32 partials), BK=64 double-barrier loop (K=1856)
// ---------------------------------------------------------------------------
__global__ __launch_bounds__(256, 2) void gemm_embed(
    const bf16_t* __restrict__ A, const bf16_t* __restrict__ B,
    float* __restrict__ Cout, size_t zstride) {
  constexpr int BM = 128, BN = 128;
  __shared__ bf16_t lsA[BM * 64];
  __shared__ bf16_t lsB[BN * 64];
  const int tid = threadIdx.x;
  const int w = tid >> 6, lane = tid & 63;
  const int wm = w >> 1, wn = w & 1;
  const int lanelo = lane & 15, quad = lane >> 4;
  const int wbase = tid & ~63;
  const int m0 = blockIdx.x * BM, n0 = blockIdx.y * BN;
  const int ktiles = KPAD >> 6;                 // 29
  const int tpz = (ktiles + 3) / 4;             // 8
  const int kb = blockIdx.z * tpz * 64;
  const int ke = min(KPAD, kb + tpz * 64);
  f32x4 acc[4][4] = {};

  for (int kt = kb; kt < ke; kt += 64) {
    __syncthreads();
#pragma unroll
    for (int rr = 0; rr < 4; ++rr) {
      int chunk = rr * 256 + tid;
      int r = chunk >> 3, c8 = chunk & 7;
      int lg = c8 ^ (r & 7);
      async_cp16(A + (size_t)(m0 + r) * KPAD + kt + lg * 8,
                 lsA + (size_t)(rr * 256 + wbase) * 8);
    }
#pragma unroll
    for (int rr = 0; rr < 4; ++rr) {
      int chunk = rr * 256 + tid;
      int r = chunk >> 3, c8 = chunk & 7;
      int lg = c8 ^ (r & 7);
      async_cp16(B + (size_t)(n0 + r) * KPAD + kt + lg * 8,
                 lsB + (size_t)(rr * 256 + wbase) * 8);
    }
    __syncthreads();
    bf16x8 af[4][2], bfv[4][2];
#pragma unroll
    for (int i = 0; i < 4; ++i) {
      int r = wm * 64 + i * 16 + lanelo;
#pragma unroll
      for (int kk = 0; kk < 2; ++kk)
        af[i][kk] = *(const bf16x8*)(lsA + (size_t)(r * 8 + ((kk * 4 + quad) ^ (r & 7))) * 8);
    }
#pragma unroll
    for (int j = 0; j < 4; ++j) {
      int r = wn * 64 + j * 16 + lanelo;
#pragma unroll
      for (int kk = 0; kk < 2; ++kk)
        bfv[j][kk] = *(const bf16x8*)(lsB + (size_t)(r * 8 + ((kk * 4 + quad) ^ (r & 7))) * 8);
    }
#pragma unroll
    for (int kk = 0; kk < 2; ++kk)
#pragma unroll
      for (int i = 0; i < 4; ++i)
#pragma unroll
        for (int j = 0; j < 4; ++j)
          acc[i][j] = mfma16(af[i][kk], bfv[j][kk], acc[i][j]);
  }
#pragma unroll
  for (int i = 0; i < 4; ++i)
#pragma unroll
    for (int j = 0; j < 4; ++j)
#pragma unroll
      for (int reg = 0; reg < 4; ++reg) {
        const int m = m0 + wm * 64 + i * 16 + quad * 4 + reg;
        const int n = n0 + wn * 64 + j * 16 + lanelo;
        (Cout + (size_t)blockIdx.z * zstride)[(size_t)m * D_ + n] =
            acc[i][j][reg];
      }
}

// ---------------------------------------------------------------------------
// Fused-LN GEMM: C[M,N] = LN(X)[M,256] * Bw[N,256]^T + bias (-> bf16, EP2 relu)
// Full K=256 LDS-resident; ONE barrier. grid (M/64, N/64).
// A swizzle: slot (c+r)&7 rotate; B swizzle: c^(r&7) (async-staged).
// ---------------------------------------------------------------------------
template <int EP>  // 1: bias, 2: bias+relu
__global__ __launch_bounds__(256, 2) void gemm_ln(
    const float* __restrict__ X, const float* __restrict__ g,
    const float* __restrict__ b, const bf16_t* __restrict__ Bw,
    const float* __restrict__ bias, bf16_t* __restrict__ Cout, int ldc) {
  __shared__ bf16_t lsA[64 * 256];
  __shared__ bf16_t lsB[64 * 256];
  const int tid = threadIdx.x;
  const int w = tid >> 6, lane = tid & 63;
  const int wm = w >> 1, wn = w & 1;
  const int lanelo = lane & 15, quad = lane >> 4;
  const int wbase = tid & ~63;
  const int m0 = blockIdx.x * 64, n0 = blockIdx.y * 64;

  // B full-K async staging
#pragma unroll
  for (int rr = 0; rr < 8; ++rr) {
    int ch = rr * 256 + tid;
    int r = ch >> 5, kb = (ch >> 3) & 3, c = ch & 7;
    int lg = c ^ (r & 7);
    async_cp16(Bw + (size_t)(n0 + r) * 256 + kb * 64 + lg * 8,
               lsB + (size_t)(rr * 256 + wbase) * 8);
  }
  // A: LN in registers (4 lanes per row), write swizzled bf16 to LDS
  {
    const int ar = tid >> 2, aq = tid & 3;
    const float4* xrow = (const float4*)(X + (size_t)(m0 + ar) * 256) + aq * 16;
    float4 xv[16];
    float sum = 0.f;
#pragma unroll
    for (int i = 0; i < 16; ++i) {
      xv[i] = xrow[i];
      sum += xv[i].x + xv[i].y + xv[i].z + xv[i].w;
    }
    sum += __shfl_xor(sum, 1);
    sum += __shfl_xor(sum, 2);
    const float mean = sum * (1.f / 256.f);
    float ss = 0.f;
#pragma unroll
    for (int i = 0; i < 16; ++i) {
      float a0 = xv[i].x - mean, a1 = xv[i].y - mean;
      float a2 = xv[i].z - mean, a3 = xv[i].w - mean;
      ss += a0 * a0 + a1 * a1 + a2 * a2 + a3 * a3;
    }
    ss += __shfl_xor(ss, 1);
    ss += __shfl_xor(ss, 2);
    const float rs = rsqrtf(ss * (1.f / 256.f) + 1e-12f);
    const float4* gg4 = (const float4*)g + aq * 16;
    const float4* bb4 = (const float4*)b + aq * 16;
#pragma unroll
    for (int c = 0; c < 8; ++c) {
      float4 v0 = xv[c * 2], v1 = xv[c * 2 + 1];
      float4 g0 = gg4[c * 2], g1 = gg4[c * 2 + 1];
      float4 b0 = bb4[c * 2], b1 = bb4[c * 2 + 1];
      bf16x8 o;
      o[0] = (bf16_t)((v0.x - mean) * rs * g0.x + b0.x);
      o[1] = (bf16_t)((v0.y - mean) * rs * g0.y + b0.y);
      o[2] = (bf16_t)((v0.z - mean) * rs * g0.z + b0.z);
      o[3] = (bf16_t)((v0.w - mean) * rs * g0.w + b0.w);
      o[4] = (bf16_t)((v1.x - mean) * rs * g1.x + b1.x);
      o[5] = (bf16_t)((v1.y - mean) * rs * g1.y + b1.y);
      o[6] = (bf16_t)((v1.z - mean) * rs * g1.z + b1.z);
      o[7] = (bf16_t)((v1.w - mean) * rs * g1.w + b1.w);
      *(bf16x8*)(lsA + (size_t)ar * 256 + (aq * 8 + ((c + ar) & 7)) * 8) = o;
    }
  }
  __syncthreads();  // drains async B too

  f32x4 acc[2][2] = {};
#pragma unroll
  for (int kb = 0; kb < 4; ++kb) {
    bf16x8 af[2][2], bfv[2][2];
#pragma unroll
    for (int i = 0; i < 2; ++i) {
      int r = wm * 32 + i * 16 + lanelo;
#pragma unroll
      for (int kk = 0; kk < 2; ++kk)
        af[i][kk] = *(const bf16x8*)(lsA + (size_t)r * 256 +
                                     (kb * 8 + ((kk * 4 + quad + r) & 7)) * 8);
    }
#pragma unroll
    for (int j = 0; j < 2; ++j) {
      int r = wn * 32 + j * 16 + lanelo;
#pragma unroll
      for (int kk = 0; kk < 2; ++kk)
        bfv[j][kk] = *(const bf16x8*)(lsB + (size_t)r * 256 +
                                      (kb * 8 + ((kk * 4 + quad) ^ (r & 7))) * 8);
    }
#pragma unroll
    for (int kk = 0; kk < 2; ++kk)
#pragma unroll
      for (int i = 0; i < 2; ++i)
#pragma unroll
        for (int j = 0; j < 2; ++j)
          acc[i][j] = mfma16(af[i][kk], bfv[j][kk], acc[i][j]);
  }

#pragma unroll
  for (int i = 0; i < 2; ++i)
#pragma unroll
    for (int j = 0; j < 2; ++j)
#pragma unroll
      for (int reg = 0; reg < 4; ++reg) {
        const int m = m0 + wm * 32 + i * 16 + quad * 4 + reg;
        const int n = n0 + wn * 32 + j * 16 + lanelo;
        float v = acc[i][j][reg] + bias[n];
        if (EP == 2) v = fmaxf(v, 0.f);
        Cout[(size_t)m * ldc + n] = (bf16_t)v;
      }
}

// ---------------------------------------------------------------------------
// Wo GEMM: A = combined attention splits (fused), full K=256 resident.
// Epilogue: x[m][n] += C + bo[n]  (disjoint tiles -> plain RMW).
// grid (NROW/64, 4)
// ---------------------------------------------------------------------------
__global__ __launch_bounds__(256, 2) void wo_fused(
    const bf16_t* __restrict__ Opart, const float* __restrict__ mpart,
    const float* __restrict__ lpart, const bf16_t* __restrict__ Bw,
    const float* __restrict__ bo, float* __restrict__ x) {
  __shared__ bf16_t lsA[64 * 256];
  __shared__ bf16_t lsB[64 * 256];
  __shared__ float lswgt[64 * 4 * 4];  // [r][h][p]
  const int tid = threadIdx.x;
  const int w = tid >> 6, lane = tid & 63;
  const int wm = w >> 1, wn = w & 1;
  const int lanelo = lane & 15, quad = lane >> 4;
  const int wbase = tid & ~63;
  const int m0 = blockIdx.x * 64, n0 = blockIdx.y * 64;
  const int bb = m0 >> 9, t0 = m0 & 511;

  // B full-K async staging
#pragma unroll
  for (int rr = 0; rr < 8; ++rr) {
    int ch = rr * 256 + tid;
    int r = ch >> 5, kb = (ch >> 3) & 3, c = ch & 7;
    int lg = c ^ (r & 7);
    async_cp16(Bw + (size_t)(n0 + r) * 256 + kb * 64 + lg * 8,
               lsB + (size_t)(rr * 256 + wbase) * 8);
  }
  // split-combine weights: thread = (row r, head h)
  {
    const int r = tid >> 2, h = tid & 3;
    const int bh = bb * 4 + h;
    const int t = t0 + r;
    float mp[NSA], lp[NSA];
    float mmax = -__builtin_inff();
#pragma unroll
    for (int p = 0; p < NSA; ++p) {
      const size_t prow = ((size_t)p * NBH + bh) * T_ + t;
      mp[p] = mpart[prow]; lp[p] = lpart[prow];
      mmax = fmaxf(mmax, mp[p]);
    }
    float e[NSA], denom = 0.f;
#pragma unroll
    for (int p = 0; p < NSA; ++p) {
      e[p] = __expf(mp[p] - mmax);
      denom += lp[p] * e[p];
    }
    const float inv = (denom > 0.f) ? 1.f / denom : 0.f;
#pragma unroll
    for (int p = 0; p < NSA; ++p) lswgt[(r * 4 + h) * 4 + p] = e[p] * inv;
  }
  __syncthreads();
  // A staging: weighted sum of 4 split partials -> swizzled LDS
  {
    const int kb = (tid >> 3) & 3, c = tid & 7;
    const int bh = bb * 4 + kb;
#pragma unroll
    for (int rr = 0; rr < 8; ++rr) {
      const int r = (tid >> 5) + 8 * rr;
      const int t = t0 + r;
      float cv[8] = {};
#pragma unroll
      for (int p = 0; p < NSA; ++p) {
        const float wgt = lswgt[(r * 4 + kb) * 4 + p];
        bf16x8 op = *(const bf16x8*)(Opart +
            (((size_t)p * NBH + bh) * T_ + t) * 64 + c * 8);
#pragma unroll
        for (int i = 0; i < 8; ++i) cv[i] += wgt * (float)op[i];
      }
      bf16x8 o;
#pragma unroll
      for (int i = 0; i < 8; ++i) o[i] = (bf16_t)cv[i];
      *(bf16x8*)(lsA + (size_t)r * 256 + (kb * 8 + ((c + r) & 7)) * 8) = o;
    }
  }
  __syncthreads();

  f32x4 acc[2][2] = {};
#pragma unroll
  for (int kb = 0; kb < 4; ++kb) {
    bf16x8 af[2][2], bfv[2][2];
#pragma unroll
    for (int i = 0; i < 2; ++i) {
      int r = wm * 32 + i * 16 + lanelo;
#pragma unroll
      for (int kk = 0; kk < 2; ++kk)
        af[i][kk] = *(const bf16x8*)(lsA + (size_t)r * 256 +
                                     (kb * 8 + ((kk * 4 + quad + r) & 7)) * 8);
    }
#pragma unroll
    for (int j = 0; j < 2; ++j) {
      int r = wn * 32 + j * 16 + lanelo;
#pragma unroll
      for (int kk = 0; kk < 2; ++kk)
        bfv[j][kk] = *(const bf16x8*)(lsB + (size_t)r * 256 +
                                      (kb * 8 + ((kk * 4 + quad) ^ (r & 7))) * 8);
    }
#pragma unroll
    for (int kk = 0; kk < 2; ++kk)
#pragma unroll
      for (int i = 0; i < 2; ++i)
#pragma unroll
        for (int j = 0; j < 2; ++j)
          acc[i][j] = mfma16(af[i][kk], bfv[j][kk], acc[i][j]);
  }

#pragma unroll
  for (int i = 0; i < 2; ++i)
#pragma unroll
    for (int j = 0; j < 2; ++j)
#pragma unroll
      for (int reg = 0; reg < 4; ++reg) {
        const int m = m0 + wm * 32 + i * 16 + quad * 4 + reg;
        const int n = n0 + wn * 32 + j * 16 + lanelo;
        const size_t idx = (size_t)m * D_ + n;
        x[idx] = x[idx] + acc[i][j][reg] + bo[n];
      }
}

// ---------------------------------------------------------------------------
// FF2: C = A[4096,2048] * W2[256,2048]^T, split-K=2, atomicAdd into x (+b2@z0)
// grid (64, 4, 2), BK=64 double-barrier loop.
// ---------------------------------------------------------------------------
__global__ __launch_bounds__(256, 3) void ff2_gemm(
    const bf16_t* __restrict__ A, const bf16_t* __restrict__ Bw,
    const float* __restrict__ b2, float* __restrict__ x) {
  __shared__ bf16_t lsA[64 * 64];
  __shared__ bf16_t lsB[64 * 64];
  const int tid = threadIdx.x;
  const int w = tid >> 6, lane = tid & 63;
  const int wm = w >> 1, wn = w & 1;
  const int lanelo = lane & 15, quad = lane >> 4;
  const int wbase = tid & ~63;
  const int m0 = blockIdx.x * 64, n0 = blockIdx.y * 64;
  const int z = blockIdx.z;
  f32x4 acc[2][2] = {};

  for (int kt = z * 1024; kt < z * 1024 + 1024; kt += 64) {
    __syncthreads();
#pragma unroll
    for (int rr = 0; rr < 2; ++rr) {
      int chunk = rr * 256 + tid;
      int r = chunk >> 3, c8 = chunk & 7;
      int lg = c8 ^ (r & 7);
      async_cp16(A + (size_t)(m0 + r) * FF_ + kt + lg * 8,
                 lsA + (size_t)(rr * 256 + wbase) * 8);
    }
#pragma unroll
    for (int rr = 0; rr < 2; ++rr) {
      int chunk = rr * 256 + tid;
      int r = chunk >> 3, c8 = chunk & 7;
      int lg = c8 ^ (r & 7);
      async_cp16(Bw + (size_t)(n0 + r) * FF_ + kt + lg * 8,
                 lsB + (size_t)(rr * 256 + wbase) * 8);
    }
    __syncthreads();
    bf16x8 af[2][2], bfv[2][2];
#pragma unroll
    for (int i = 0; i < 2; ++i) {
      int r = wm * 32 + i * 16 + lanelo;
#pragma unroll
      for (int kk = 0; kk < 2; ++kk)
        af[i][kk] = *(const bf16x8*)(lsA + (size_t)(r * 8 + ((kk * 4 + quad) ^ (r & 7))) * 8);
    }
#pragma unroll
    for (int j = 0; j < 2; ++j) {
      int r = wn * 32 + j * 16 + lanelo;
#pragma unroll
      for (int kk = 0; kk < 2; ++kk)
        bfv[j][kk] = *(const bf16x8*)(lsB + (size_t)(r * 8 + ((kk * 4 + quad) ^ (r & 7))) * 8);
    }
#pragma unroll
    for (int kk = 0; kk < 2; ++kk)
#pragma unroll
      for (int i = 0; i < 2; ++i)
#pragma unroll
        for (int j = 0; j < 2; ++j)
          acc[i][j] = mfma16(af[i][kk], bfv[j][kk], acc[i][j]);
  }

#pragma unroll
  for (int i = 0; i < 2; ++i)
#pragma unroll
    for (int j = 0; j < 2; ++j)
#pragma unroll
      for (int reg = 0; reg < 4; ++reg) {
        const int m = m0 + wm * 32 + i * 16 + quad * 4 + reg;
        const int n = n0 + wn * 32 + j * 16 + lanelo;
        float v = acc[i][j][reg];
        if (z == 0) v += b2[n];
        atomicAdd(x + (size_t)m * D_ + n, v);
      }
}

// ---------------------------------------------------------------------------
// Fused flash attention w/ LDS-resident rel-pos bias (unchanged from R4).
// grid (T/64, NBH, NSA); LDS 50.5 KB -> 3 blocks/CU.
// ---------------------------------------------------------------------------
__global__ __launch_bounds__(256, 3) void attn_fused(
    const bf16_t* __restrict__ qkv, const bf16_t* __restrict__ pkn,
    const int* __restrict__ masks, bf16_t* __restrict__ Opart,
    float* __restrict__ mpart, float* __restrict__ lpart) {
  __shared__ bf16_t ls_qp[64 * 72];
  __shared__ bf16_t ls_pkr[64 * 196];
  __shared__ bf16_t ls_k[64 * 64];
  __shared__ bf16_t ls_vt[64 * 72];

  const int tid = threadIdx.x, w = tid >> 6, lane = tid & 63;
  const int lanelo = lane & 15, quad = lane >> 4;
  const int wbase = tid & ~63;
  const int t0 = blockIdx.x * 64;
  const int bh = blockIdx.y, bb = bh >> 2, h = bh & 3;
  const int z = blockIdx.z;
  const size_t rowbase = (size_t)bb * T_;
  const int jb = t0 - 128 * z + 873;

#pragma unroll
  for (int rr = 0; rr < 2; ++rr) {
    int chunk = rr * 256 + tid;
    int r = chunk >> 3, c8 = chunk & 7;
    int lg = c8 ^ (r & 7);
    async_cp16(qkv + (rowbase + t0 + r) * 768 + h * 64 + lg * 8,
               ls_qp + (size_t)(rr * 256 + wbase) * 8);
  }
#pragma unroll
  for (int rr = 0; rr < 6; ++rr) {
    int chunk = rr * 256 + tid;
    int r = chunk >> 3, c8 = chunk & 7;
    int lg = c8 ^ (r & 7);
    async_cp16(pkn + (size_t)(jb + r) * DK + lg * 8,
               ls_pkr + (size_t)(rr * 256 + wbase) * 8);
  }
  __syncthreads();
  bf16x8 qf[2];
#pragma unroll
  for (int kk = 0; kk < 2; ++kk) {
    int r = w * 16 + lanelo;
    qf[kk] = *(const bf16x8*)(ls_pkr + 0);  // placeholder avoided below
  }
  // (re-read correctly; compiler folds)
#pragma unroll
  for (int kk = 0; kk < 2; ++kk) {
    int r = w * 16 + lanelo;
    qf[kk] = *(const bf16x8*)(ls_qp + (size_t)(r * 8 + ((kk * 4 + quad) ^ (r & 7))) * 8);
  }
  f32x4 racc[12] = {};
#pragma unroll
  for (int kk = 0; kk < 2; ++kk)
#pragma unroll
    for (int nf = 0; nf < 12; ++nf) {
      int r = nf * 16 + lanelo;
      bf16x8 bj = *(const bf16x8*)(ls_pkr + (size_t)(r * 8 + ((kk * 4 + quad) ^ (r & 7))) * 8);
      racc[nf] = mfma16(qf[kk], bj, racc[nf]);
    }
  __syncthreads();
#pragma unroll
  for (int nf = 0; nf < 12; ++nf)
#pragma unroll
    for (int reg = 0; reg < 4; ++reg)
      ls_pkr[(w * 16 + quad * 4 + reg) * 196 + nf * 16 + lanelo] =
          (bf16_t)racc[nf][reg];

  f32x4 o_acc[4] = {};
  float m_run[4], l_run[4];
#pragma unroll
  for (int i = 0; i < 4; ++i) { m_run[i] = -__builtin_inff(); l_run[i] = 0.f; }

  for (int stl = 0; stl < 2; ++stl) {
    const int s0 = 128 * z + 64 * stl;
    __syncthreads();
#pragma unroll
    for (int rr = 0; rr < 2; ++rr) {
      int chunk = rr * 256 + tid;
      int r = chunk >> 3, c8 = chunk & 7;
      int lg = c8 ^ (r & 7);
      async_cp16(qkv + (rowbase + s0 + r) * 768 + 256 + h * 64 + lg * 8,
                 ls_k + (size_t)(rr * 256 + wbase) * 8);
    }
#pragma unroll
    for (int c = tid; c < 64 * 8; c += 256) {
      int r = c & 63, d0 = (c >> 6) * 8;
      bf16x8 vv = *(const bf16x8*)(qkv + (rowbase + s0 + r) * 768 + 512 + h * 64 + d0);
#pragma unroll
      for (int i = 0; i < 8; ++i) ls_vt[(d0 + i) * 72 + r] = vv[i];
    }
    int mk[4];
#pragma unroll
    for (int nf = 0; nf < 4; ++nf)
      mk[nf] = masks[bb * T_ + s0 + nf * 16 + lanelo];
    __syncthreads();

    f32x4 sacc[4] = {};
#pragma unroll
    for (int kk = 0; kk < 2; ++kk)
#pragma unroll
      for (int nf = 0; nf < 4; ++nf) {
        int r = nf * 16 + lanelo;
        bf16x8 bk = *(const bf16x8*)(ls_k + (size_t)(r * 8 + ((kk * 4 + quad) ^ (r & 7))) * 8);
        sacc[nf] = mfma16(qf[kk], bk, sacc[nf]);
      }
    float sv[4][4];
#pragma unroll
    for (int nf = 0; nf < 4; ++nf) {
      const int scol = nf * 16 + lanelo;
#pragma unroll
      for (int reg = 0; reg < 4; ++reg) {
        const int trow = w * 16 + quad * 4 + reg;
        const float bt = (float)ls_pkr[trow * 196 + (trow - scol - 64 * stl + 127)];
        sv[nf][reg] = mk[nf] ? (sacc[nf][reg] + bt) * 0.125f : -3.4028235e38f;
      }
    }
    float alpha[4];
#pragma unroll
    for (int reg = 0; reg < 4; ++reg) {
      float bm = fmaxf(fmaxf(sv[0][reg], sv[1][reg]), fmaxf(sv[2][reg], sv[3][reg]));
#pragma unroll
      for (int o = 1; o < 16; o <<= 1) bm = fmaxf(bm, __shfl_xor(bm, o));
      const float mn = fmaxf(m_run[reg], bm);
      alpha[reg] = __expf(m_run[reg] - mn);
      m_run[reg] = mn;
      float rsum = 0.f;
#pragma unroll
      for (int nf = 0; nf < 4; ++nf) {
        float p = __expf(sv[nf][reg] - mn) * (mk[nf] ? 1.f : 0.f);
        sv[nf][reg] = p;
        rsum += p;
      }
#pragma unroll
      for (int o = 1; o < 16; o <<= 1) rsum += __shfl_xor(rsum, o);
      l_run[reg] = l_run[reg] * alpha[reg] + rsum;
    }
#pragma unroll
    for (int nf = 0; nf < 4; ++nf)
#pragma unroll
      for (int reg = 0; reg < 4; ++reg) {
        o_acc[nf][reg] *= alpha[reg];
        ls_qp[(w * 16 + quad * 4 + reg) * 72 + nf * 16 + lanelo] = (bf16_t)sv[nf][reg];
      }
#pragma unroll
    for (int kk = 0; kk < 2; ++kk) {
      bf16x8 ap = *(const bf16x8*)&ls_qp[(w * 16 + lanelo) * 72 + kk * 32 + quad * 8];
#pragma unroll
      for (int nf = 0; nf < 4; ++nf) {
        bf16x8 bv = *(const bf16x8*)&ls_vt[(nf * 16 + lanelo) * 72 + kk * 32 + quad * 8];
        o_acc[nf] = mfma16(ap, bv, o_acc[nf]);
      }
    }
  }

#pragma unroll
  for (int reg = 0; reg < 4; ++reg) {
    const int trow = w * 16 + quad * 4 + reg;
    const size_t prow = ((size_t)z * NBH + bh) * T_ + t0 + trow;
#pragma unroll
    for (int nf = 0; nf < 4; ++nf)
      Opart[prow * 64 + nf * 16 + lanelo] = (bf16_t)o_acc[nf][reg];
    if (lanelo == 0) { mpart[prow] = m_run[reg]; lpart[prow] = l_run[reg]; }
  }
}

// ---------------------------------------------------------------------------
// host
// ---------------------------------------------------------------------------
extern "C" void kernel_launch(void* const* d_in, const int* in_sizes, int n_in,
                              void* d_out, int out_size, void* d_ws, size_t ws_size,
                              hipStream_t stream) {
  const float* xs       = (const float*)d_in[0];
  const int*   masks    = (const int*)d_in[1];
  const float* emb_w    = (const float*)d_in[2];
  const float* emb_b    = (const float*)d_in[3];
  const float* emb_g    = (const float*)d_in[4];
  const float* emb_beta = (const float*)d_in[5];
  const float* pe_k     = (const float*)d_in[6];
  const float* Wq       = (const float*)d_in[7];
  const float* bq       = (const float*)d_in[8];
  const float* Wk       = (const float*)d_in[9];
  const float* bk       = (const float*)d_in[10];
  const float* Wv       = (const float*)d_in[11];
  const float* bv       = (const float*)d_in[12];
  const float* Wo       = (const float*)d_in[13];
  const float* bo       = (const float*)d_in[14];
  const float* ln1_g    = (const float*)d_in[15];
  const float* ln1_b    = (const float*)d_in[16];
  const float* ln2_g    = (const float*)d_in[17];
  const float* ln2_b    = (const float*)d_in[18];
  const float* lnk_g    = (const float*)d_in[19];
  const float* lnk_b    = (const float*)d_in[20];
  const float* W1       = (const float*)d_in[21];
  const float* b1       = (const float*)d_in[22];
  const float* W2       = (const float*)d_in[23];
  const float* b2       = (const float*)d_in[24];
  const float* after_g  = (const float*)d_in[25];
  const float* after_b  = (const float*)d_in[26];

  char* ws = (char*)d_ws;
  size_t off = 0;
  auto take = [&](size_t bytes) -> void* {
    void* p = ws + off;
    off += (bytes + 255) & ~(size_t)255;
    return p;
  };
  bf16_t* ewb  = (bf16_t*)take((size_t)D_ * KPAD * 2);
  bf16_t* wcat = (bf16_t*)take((size_t)L_ * 768 * D_ * 2);
  float*  bcat = (float*) take((size_t)L_ * 768 * 4);
  bf16_t* wob  = (bf16_t*)take((size_t)L_ * D_ * D_ * 2);
  bf16_t* w1b  = (bf16_t*)take((size_t)L_ * FF_ * D_ * 2);
  bf16_t* w2b  = (bf16_t*)take((size_t)L_ * D_ * FF_ * 2);
  bf16_t* pknb = (bf16_t*)take((size_t)L_ * PKROWS * DK * 2);
  float*  x    = (float*) take((size_t)NROW * D_ * 4);
  bf16_t* qkv  = (bf16_t*)take((size_t)NROW * 768 * 2);
  bf16_t* hbuf = (bf16_t*)take((size_t)NROW * FF_ * 2);
  bf16_t* Opart = (bf16_t*)take((size_t)NSA * NBH * T_ * 64 * 2);
  float*  mpart = (float*)take((size_t)NSA * NBH * T_ * 4);
  float*  lpart = (float*)take((size_t)NSA * NBH * T_ * 4);
  float*  gpart = (float*)take((size_t)4 * NROW * D_ * 4);
  bf16_t* xsb  = hbuf;  // xs bf16 only needed before first FF1
  const size_t ZS = (size_t)NROW * D_;

  // prep
  cvt_pad_row<<<NROW, 256, 0, stream>>>(xs, xsb, IDIM, KPAD);
  cvt_pad_row<<<D_, 256, 0, stream>>>(emb_w, ewb, IDIM, KPAD);
  prep_all<<<4096, 256, 0, stream>>>(Wq, Wk, Wv, Wo, W1, W2, bq, bk, bv,
                                     wcat, wob, w1b, w2b, bcat);
  pkn_ln<<<(L_ * PKROWS) / 4, 256, 0, stream>>>(pe_k, lnk_g, lnk_b, pknb);

  // embed: split-K=4 GEMM -> combine (x = relu(LN(.)))
  gemm_embed<<<dim3(NROW / 128, D_ / 128, 4), 256, 0, stream>>>(xsb, ewb, gpart, ZS);
  embed_combine<<<NROW / 4, 256, 0, stream>>>(gpart, emb_b, emb_g, emb_beta, x);

  for (int l = 0; l < L_; ++l) {
    // QKV = LN1(x) @ Wqkv^T + b   (fused LN, one barrier)
    gemm_ln<1><<<dim3(NROW / 64, 768 / 64), 256, 0, stream>>>(
        x, ln1_g + l * D_, ln1_b + l * D_, wcat + (size_t)l * 768 * D_,
        bcat + l * 768, qkv, 768);
    // flash attention partials
    attn_fused<<<dim3(T_ / 64, NBH, NSA), 256, 0, stream>>>(
        qkv, pknb + (size_t)l * PKROWS * DK, masks, Opart, mpart, lpart);
    // x += combine(Opart) @ Wo^T + bo
    wo_fused<<<dim3(NROW / 64, D_ / 64), 256, 0, stream>>>(
        Opart, mpart, lpart, wob + (size_t)l * D_ * D_, bo + l * D_, x);
    // hbuf = relu(LN2(x) @ W1^T + b1)   (fused LN, one barrier)
    gemm_ln<2><<<dim3(NROW / 64, FF_ / 64), 256, 0, stream>>>(
        x, ln2_g + l * D_, ln2_b + l * D_, w1b + (size_t)l * FF_ * D_,
        b1 + l * FF_, hbuf, FF_);
    // x += hbuf @ W2^T + b2  (split-K=2, atomic epilogue)
    ff2_gemm<<<dim3(NROW / 64, D_ / 64, 2), 256, 0, stream>>>(
        hbuf, w2b + (size_t)l * D_ * FF_, b2 + l * D_, x);
  }
  ln_rows_f32<<<NROW / 4, 256, 0, stream>>>(x, after_g, after_b, (float*)d_out);
}

// Round 6
// 1304.054 us; speedup vs baseline: 1.6123x; 1.6123x over previous
//
#include <hip/hip_runtime.h>
#include <cstdint>

// ---------------------------------------------------------------------------
// EETransformerEncoder on MI355X (gfx950).  Round 6 = Round 4 structure +
// consolidated prep + software-pipelined attention front-end.
// R5 lesson: full-K one-barrier GEMM w/ LN-in-staging = 2.8% MfmaUtil (LN
// recomputed per N-block, tiny compute per block). LN stays fused in the
// PRODUCER epilogue (add_combine_ln), GEMMs keep BK=64 multi-barrier loop.
// ---------------------------------------------------------------------------

typedef __bf16 bf16_t;
typedef bf16_t bf16x4 __attribute__((ext_vector_type(4)));
typedef bf16_t bf16x8 __attribute__((ext_vector_type(8)));
typedef float  f32x4  __attribute__((ext_vector_type(4)));

#define B_    8
#define T_    512
#define IDIM  1799
#define KPAD  1856        // 29*64
#define D_    256
#define H_    4
#define DK    64
#define FF_   2048
#define L_    16
#define NROW  4096        // B_*T_
#define PKROWS 2000       // 2*MAXLEN
#define NBH   32          // B_*H_
#define NSA   4           // attention s-splits

__device__ __forceinline__ f32x4 mfma16(bf16x8 a, bf16x8 b, f32x4 c) {
  return __builtin_amdgcn_mfma_f32_16x16x32_bf16(a, b, c, 0, 0, 0);
}

__device__ __forceinline__ void async_cp16(const void* g, void* l) {
  __builtin_amdgcn_global_load_lds(
      (__attribute__((address_space(1))) void*)(g),
      (__attribute__((address_space(3))) void*)(l), 16, 0, 0);
}

// ---------------------------------------------------------------------------
// prep: all weight conversions/packing in one grid-stride kernel
// ---------------------------------------------------------------------------
#define WCAT_N (L_ * 768 * 256)
#define WOB_N  (L_ * 256 * 256)
#define W1B_N  (L_ * 2048 * 256)
#define W2B_N  (L_ * 256 * 2048)
#define BCAT_N (L_ * 768)
#define PREP_TOT (WCAT_N + WOB_N + W1B_N + W2B_N + BCAT_N)

__global__ __launch_bounds__(256) void prep_all(
    const float* __restrict__ wq, const float* __restrict__ wk,
    const float* __restrict__ wv, const float* __restrict__ wo,
    const float* __restrict__ w1, const float* __restrict__ w2,
    const float* __restrict__ bq, const float* __restrict__ bk,
    const float* __restrict__ bv, bf16_t* __restrict__ wcat,
    bf16_t* __restrict__ wob, bf16_t* __restrict__ w1b,
    bf16_t* __restrict__ w2b, float* __restrict__ bcat) {
  const int stride = gridDim.x * 256;
  for (int i = blockIdx.x * 256 + threadIdx.x; i < PREP_TOT; i += stride) {
    int j = i;
    if (j < WCAT_N) {
      const int per_l = 768 * 256;
      int l = j / per_l, r = j - l * per_l;
      int n = r >> 8, c = r & 255;
      int sel = n >> 8, nn = n & 255;
      const float* wsrc = (sel == 0) ? wq : (sel == 1) ? wk : wv;
      wcat[j] = (bf16_t)wsrc[((size_t)l * 256 + nn) * 256 + c];
      continue;
    }
    j -= WCAT_N;
    if (j < WOB_N) { wob[j] = (bf16_t)wo[j]; continue; }
    j -= WOB_N;
    if (j < W1B_N) { w1b[j] = (bf16_t)w1[j]; continue; }
    j -= W1B_N;
    if (j < W2B_N) { w2b[j] = (bf16_t)w2[j]; continue; }
    j -= W2B_N;
    {
      int l = j / 768, n = j - l * 768;
      int sel = n >> 8, nn = n & 255;
      const float* bsrc = (sel == 0) ? bq : (sel == 1) ? bk : bv;
      bcat[j] = bsrc[l * 256 + nn];
    }
  }
}

__global__ __launch_bounds__(256) void cvt_pad_row(const float* __restrict__ s,
                                                   bf16_t* __restrict__ d,
                                                   int ksrc, int kdst) {
  const int r = blockIdx.x;
  const float* sr = s + (size_t)r * ksrc;
  bf16_t* dr = d + (size_t)r * kdst;
  for (int k = threadIdx.x; k < kdst; k += 256)
    dr[k] = (k < ksrc) ? (bf16_t)sr[k] : (bf16_t)0.f;
}

__global__ __launch_bounds__(256) void pkn_ln(const float* __restrict__ pe_k,
                                              const float* __restrict__ lnk_g,
                                              const float* __restrict__ lnk_b,
                                              bf16_t* __restrict__ out) {
  const int idx = blockIdx.x * 4 + (threadIdx.x >> 6);
  if (idx >= L_ * PKROWS) return;
  const int lane = threadIdx.x & 63;
  const int l = idx / PKROWS, r = idx - l * PKROWS;
  float v = pe_k[(size_t)r * DK + lane];
  float s = v;
#pragma unroll
  for (int o = 32; o; o >>= 1) s += __shfl_xor(s, o);
  const float mean = s * (1.f / DK);
  const float dx = v - mean;
  float q = dx * dx;
#pragma unroll
  for (int o = 32; o; o >>= 1) q += __shfl_xor(q, o);
  const float rs = rsqrtf(q * (1.f / DK) + 1e-12f);
  out[((size_t)l * PKROWS + r) * DK + lane] =
      (bf16_t)(dx * rs * lnk_g[l * DK + lane] + lnk_b[l * DK + lane]);
}

// ---------------------------------------------------------------------------
// final LayerNorm (fp32 out), one wave per row
// ---------------------------------------------------------------------------
__global__ __launch_bounds__(256) void ln_rows_f32(const float* __restrict__ src,
                                                   const float* __restrict__ g,
                                                   const float* __restrict__ b,
                                                   float* __restrict__ dst) {
  const int row = blockIdx.x * 4 + (threadIdx.x >> 6);
  const int lane = threadIdx.x & 63;
  const float4 v = ((const float4*)(src + (size_t)row * D_))[lane];
  float s = v.x + v.y + v.z + v.w;
#pragma unroll
  for (int o = 32; o; o >>= 1) s += __shfl_xor(s, o);
  const float mean = s * (1.f / D_);
  const float d0 = v.x - mean, d1 = v.y - mean, d2 = v.z - mean, d3 = v.w - mean;
  float q = d0 * d0 + d1 * d1 + d2 * d2 + d3 * d3;
#pragma unroll
  for (int o = 32; o; o >>= 1) q += __shfl_xor(q, o);
  const float rs = rsqrtf(q * (1.f / D_) + 1e-12f);
  const float4 gg = ((const float4*)g)[lane];
  const float4 bb = ((const float4*)b)[lane];
  ((float4*)(dst + (size_t)row * D_))[lane] =
      make_float4(d0 * rs * gg.x + bb.x, d1 * rs * gg.y + bb.y,
                  d2 * rs * gg.z + bb.z, d3 * rs * gg.w + bb.w);
}

// ---------------------------------------------------------------------------
// combine split-K GEMM partials: x += sum(parts)+bias; optionally y = LN(x)
// ---------------------------------------------------------------------------
template <int NS, bool WRITE_Y>
__global__ __launch_bounds__(256) void add_combine_ln(
    const float* __restrict__ parts, const float* __restrict__ bias,
    float* __restrict__ x, const float* __restrict__ g,
    const float* __restrict__ b, bf16_t* __restrict__ y) {
  const int row = blockIdx.x * 4 + (threadIdx.x >> 6);
  const int lane = threadIdx.x & 63;
  const size_t idx = (size_t)row * 64 + lane;
  float4 v = ((const float4*)x)[idx];
#pragma unroll
  for (int p = 0; p < NS; ++p) {
    float4 pv = ((const float4*)parts)[(size_t)p * NROW * 64 + idx];
    v.x += pv.x; v.y += pv.y; v.z += pv.z; v.w += pv.w;
  }
  const float4 bi = ((const float4*)bias)[lane];
  v.x += bi.x; v.y += bi.y; v.z += bi.z; v.w += bi.w;
  ((float4*)x)[idx] = v;
  if (WRITE_Y) {
    float s = v.x + v.y + v.z + v.w;
#pragma unroll
    for (int o = 32; o; o >>= 1) s += __shfl_xor(s, o);
    const float mean = s * (1.f / D_);
    const float d0 = v.x - mean, d1 = v.y - mean, d2 = v.z - mean, d3 = v.w - mean;
    float q = d0 * d0 + d1 * d1 + d2 * d2 + d3 * d3;
#pragma unroll
    for (int o = 32; o; o >>= 1) q += __shfl_xor(q, o);
    const float rs = rsqrtf(q * (1.f / D_) + 1e-12f);
    const float4 gg = ((const float4*)g)[lane];
    const float4 bb = ((const float4*)b)[lane];
    bf16x4 o4 = {(bf16_t)(d0 * rs * gg.x + bb.x), (bf16_t)(d1 * rs * gg.y + bb.y),
                 (bf16_t)(d2 * rs * gg.z + bb.z), (bf16_t)(d3 * rs * gg.w + bb.w)};
    ((bf16x4*)y)[idx] = o4;
  }
}

// embed combine: x = relu(LN(sum4(parts)+bias)); y = LN1(x) bf16
__global__ __launch_bounds__(256) void embed_combine(
    const float* __restrict__ parts, const float* __restrict__ bias,
    const float* __restrict__ g0, const float* __restrict__ b0,
    const float* __restrict__ g1, const float* __restrict__ b1,
    float* __restrict__ x, bf16_t* __restrict__ y) {
  const int row = blockIdx.x * 4 + (threadIdx.x >> 6);
  const int lane = threadIdx.x & 63;
  const size_t idx = (size_t)row * 64 + lane;
  float4 v = ((const float4*)parts)[idx];
#pragma unroll
  for (int p = 1; p < 4; ++p) {
    float4 pv = ((const float4*)parts)[(size_t)p * NROW * 64 + idx];
    v.x += pv.x; v.y += pv.y; v.z += pv.z; v.w += pv.w;
  }
  const float4 bi = ((const float4*)bias)[lane];
  v.x += bi.x; v.y += bi.y; v.z += bi.z; v.w += bi.w;
  float s = v.x + v.y + v.z + v.w;
#pragma unroll
  for (int o = 32; o; o >>= 1) s += __shfl_xor(s, o);
  float mean = s * (1.f / D_);
  float d0 = v.x - mean, d1 = v.y - mean, d2 = v.z - mean, d3 = v.w - mean;
  float q = d0 * d0 + d1 * d1 + d2 * d2 + d3 * d3;
#pragma unroll
  for (int o = 32; o; o >>= 1) q += __shfl_xor(q, o);
  float rs = rsqrtf(q * (1.f / D_) + 1e-12f);
  const float4 gg = ((const float4*)g0)[lane];
  const float4 bb = ((const float4*)b0)[lane];
  float x0 = fmaxf(d0 * rs * gg.x + bb.x, 0.f);
  float x1 = fmaxf(d1 * rs * gg.y + bb.y, 0.f);
  float x2 = fmaxf(d2 * rs * gg.z + bb.z, 0.f);
  float x3 = fmaxf(d3 * rs * gg.w + bb.w, 0.f);
  ((float4*)x)[idx] = make_float4(x0, x1, x2, x3);
  s = x0 + x1 + x2 + x3;
#pragma unroll
  for (int o = 32; o; o >>= 1) s += __shfl_xor(s, o);
  mean = s * (1.f / D_);
  d0 = x0 - mean; d1 = x1 - mean; d2 = x2 - mean; d3 = x3 - mean;
  q = d0 * d0 + d1 * d1 + d2 * d2 + d3 * d3;
#pragma unroll
  for (int o = 32; o; o >>= 1) q += __shfl_xor(q, o);
  rs = rsqrtf(q * (1.f / D_) + 1e-12f);
  const float4 g1v = ((const float4*)g1)[lane];
  const float4 b1v = ((const float4*)b1)[lane];
  bf16x4 o4 = {(bf16_t)(d0 * rs * g1v.x + b1v.x), (bf16_t)(d1 * rs * g1v.y + b1v.y),
               (bf16_t)(d2 * rs * g1v.z + b1v.z), (bf16_t)(d3 * rs * g1v.w + b1v.w)};
  ((bf16x4*)y)[idx] = o4;
}

// ---------------------------------------------------------------------------
// bf16 NT GEMM, BK=64: C[M,N] = A[M,K] * B[N,K]^T, split-K via blockIdx.z.
// EP: 1 bf16 bias; 2 bf16 bias+relu; 4 f32 raw partial at Cout + z*zstride
// ---------------------------------------------------------------------------
template <int BM, int BN, int EP, int MINW>
__global__ __launch_bounds__(256, MINW) void gemm_bf16(
    const bf16_t* __restrict__ A, int lda, const bf16_t* __restrict__ B, int ldb,
    const float* __restrict__ bias, void* __restrict__ Cout, int ldc,
    int K, size_t zstride) {
  constexpr int HM = BM / 2, HN = BN / 2;
  constexpr int FM = HM / 16, FN = HN / 16;
  constexpr int CA = (BM * 8) / 256, CB = (BN * 8) / 256;
  __shared__ bf16_t lsA[BM * 64];
  __shared__ bf16_t lsB[BN * 64];
  const int tid = threadIdx.x;
  const int w = tid >> 6, lane = tid & 63;
  const int wm = w >> 1, wn = w & 1;
  const int lanelo = lane & 15, quad = lane >> 4;
  const int wbase = tid & ~63;
  const int m0 = blockIdx.x * BM, n0 = blockIdx.y * BN;
  const int ktiles = K >> 6;
  const int tpz = (ktiles + gridDim.z - 1) / gridDim.z;
  const int kb = blockIdx.z * tpz * 64;
  const int ke = min(K, kb + tpz * 64);
  f32x4 acc[FM][FN] = {};

  for (int kt = kb; kt < ke; kt += 64) {
    __syncthreads();
#pragma unroll
    for (int rr = 0; rr < CA; ++rr) {
      int chunk = rr * 256 + tid;
      int r = chunk >> 3, c8 = chunk & 7;
      int lg = c8 ^ (r & 7);
      async_cp16(A + (size_t)(m0 + r) * lda + kt + lg * 8,
                 lsA + (size_t)(rr * 256 + wbase) * 8);
    }
#pragma unroll
    for (int rr = 0; rr < CB; ++rr) {
      int chunk = rr * 256 + tid;
      int r = chunk >> 3, c8 = chunk & 7;
      int lg = c8 ^ (r & 7);
      async_cp16(B + (size_t)(n0 + r) * ldb + kt + lg * 8,
                 lsB + (size_t)(rr * 256 + wbase) * 8);
    }
    __syncthreads();
    bf16x8 af[FM][2], bfv[FN][2];
#pragma unroll
    for (int i = 0; i < FM; ++i) {
      int r = wm * HM + i * 16 + lanelo;
#pragma unroll
      for (int kk = 0; kk < 2; ++kk)
        af[i][kk] = *(const bf16x8*)(lsA + (size_t)(r * 8 + ((kk * 4 + quad) ^ (r & 7))) * 8);
    }
#pragma unroll
    for (int j = 0; j < FN; ++j) {
      int r = wn * HN + j * 16 + lanelo;
#pragma unroll
      for (int kk = 0; kk < 2; ++kk)
        bfv[j][kk] = *(const bf16x8*)(lsB + (size_t)(r * 8 + ((kk * 4 + quad) ^ (r & 7))) * 8);
    }
#pragma unroll
    for (int kk = 0; kk < 2; ++kk)
#pragma unroll
      for (int i = 0; i < FM; ++i)
#pragma unroll
        for (int j = 0; j < FN; ++j)
          acc[i][j] = mfma16(af[i][kk], bfv[j][kk], acc[i][j]);
  }

#pragma unroll
  for (int i = 0; i < FM; ++i) {
#pragma unroll
    for (int j = 0; j < FN; ++j) {
#pragma unroll
      for (int reg = 0; reg < 4; ++reg) {
        const int m = m0 + wm * HM + i * 16 + quad * 4 + reg;
        const int n = n0 + wn * HN + j * 16 + lanelo;
        const size_t idx = (size_t)m * ldc + n;
        if constexpr (EP == 4) {
          ((float*)Cout + (size_t)blockIdx.z * zstride)[idx] = acc[i][j][reg];
        } else {
          float v = acc[i][j][reg] + bias[n];
          if constexpr (EP == 1) {
            ((bf16_t*)Cout)[idx] = (bf16_t)v;
          } else {
            ((bf16_t*)Cout)[idx] = (bf16_t)fmaxf(v, 0.f);
          }
        }
      }
    }
  }
}

// ---------------------------------------------------------------------------
// Wo GEMM with fused attention-split combine in A staging.
// grid (NROW/64, 2, 2): BM=64, BN=128, split-K=2 (each k-tile = one head).
// ---------------------------------------------------------------------------
__global__ __launch_bounds__(256, 2) void wo_gemm(
    const bf16_t* __restrict__ Opart, const float* __restrict__ mpart,
    const float* __restrict__ lpart, const bf16_t* __restrict__ B,
    float* __restrict__ Cout, size_t zstride) {
  __shared__ bf16_t lsA[64 * 64];
  __shared__ bf16_t lsB[128 * 64];
  const int tid = threadIdx.x;
  const int w = tid >> 6, lane = tid & 63;
  const int wm = w >> 1, wn = w & 1;
  const int lanelo = lane & 15, quad = lane >> 4;
  const int wbase = tid & ~63;
  const int m0 = blockIdx.x * 64, n0 = blockIdx.y * 128;
  const int z = blockIdx.z;
  const int bb = m0 >> 9, t0 = m0 & 511;
  f32x4 acc[2][4] = {};

  for (int kt = z * 128; kt < z * 128 + 128; kt += 64) {
    __syncthreads();
    const int hh = kt >> 6;
    const int bh = bb * 4 + hh;
#pragma unroll
    for (int rr = 0; rr < 2; ++rr) {
      int chunk = rr * 256 + tid;
      int r = chunk >> 3, c8 = chunk & 7;
      int dk0 = (c8 ^ (r & 7)) * 8;
      int t = t0 + r;
      float mp[NSA], lp[NSA];
      float mmax = -__builtin_inff();
#pragma unroll
      for (int p = 0; p < NSA; ++p) {
        const size_t prow = ((size_t)p * NBH + bh) * T_ + t;
        mp[p] = mpart[prow]; lp[p] = lpart[prow];
        mmax = fmaxf(mmax, mp[p]);
      }
      float e[NSA], denom = 0.f;
#pragma unroll
      for (int p = 0; p < NSA; ++p) {
        e[p] = __expf(mp[p] - mmax);
        denom += lp[p] * e[p];
      }
      const float inv = (denom > 0.f) ? 1.f / denom : 0.f;
      float cv[8] = {};
#pragma unroll
      for (int p = 0; p < NSA; ++p) {
        const float wgt = e[p] * inv;
        bf16x8 op = *(const bf16x8*)(Opart +
            (((size_t)p * NBH + bh) * T_ + t) * 64 + dk0);
#pragma unroll
        for (int i = 0; i < 8; ++i) cv[i] += wgt * (float)op[i];
      }
      bf16x8 rv;
#pragma unroll
      for (int i = 0; i < 8; ++i) rv[i] = (bf16_t)cv[i];
      *(bf16x8*)(lsA + (size_t)chunk * 8) = rv;
    }
#pragma unroll
    for (int rr = 0; rr < 4; ++rr) {
      int chunk = rr * 256 + tid;
      int r = chunk >> 3, c8 = chunk & 7;
      int lg = c8 ^ (r & 7);
      async_cp16(B + (size_t)(n0 + r) * 256 + kt + lg * 8,
                 lsB + (size_t)(rr * 256 + wbase) * 8);
    }
    __syncthreads();
    bf16x8 af[2][2], bfv[4][2];
#pragma unroll
    for (int i = 0; i < 2; ++i) {
      int r = wm * 32 + i * 16 + lanelo;
#pragma unroll
      for (int kk = 0; kk < 2; ++kk)
        af[i][kk] = *(const bf16x8*)(lsA + (size_t)(r * 8 + ((kk * 4 + quad) ^ (r & 7))) * 8);
    }
#pragma unroll
    for (int j = 0; j < 4; ++j) {
      int r = wn * 64 + j * 16 + lanelo;
#pragma unroll
      for (int kk = 0; kk < 2; ++kk)
        bfv[j][kk] = *(const bf16x8*)(lsB + (size_t)(r * 8 + ((kk * 4 + quad) ^ (r & 7))) * 8);
    }
#pragma unroll
    for (int kk = 0; kk < 2; ++kk)
#pragma unroll
      for (int i = 0; i < 2; ++i)
#pragma unroll
        for (int j = 0; j < 4; ++j)
          acc[i][j] = mfma16(af[i][kk], bfv[j][kk], acc[i][j]);
  }

#pragma unroll
  for (int i = 0; i < 2; ++i)
#pragma unroll
    for (int j = 0; j < 4; ++j)
#pragma unroll
      for (int reg = 0; reg < 4; ++reg) {
        const int m = m0 + wm * 32 + i * 16 + quad * 4 + reg;
        const int n = n0 + wn * 64 + j * 16 + lanelo;
        (Cout + (size_t)z * zstride)[(size_t)m * D_ + n] = acc[i][j][reg];
      }
}

// ---------------------------------------------------------------------------
// Fused flash attention w/ LDS-resident rel-pos bias, pipelined front-end:
// q/pk/K0/V0/mask staged before barrier 1; R GEMM hides tile-0 latency.
// grid (T/64, NBH, NSA); LDS 50.5 KB -> 3 blocks/CU; 4 barriers total.
// ---------------------------------------------------------------------------
__global__ __launch_bounds__(256, 3) void attn_fused(
    const bf16_t* __restrict__ qkv, const bf16_t* __restrict__ pkn,
    const int* __restrict__ masks, bf16_t* __restrict__ Opart,
    float* __restrict__ mpart, float* __restrict__ lpart) {
  __shared__ bf16_t ls_qp[64 * 72];    // q staged (64x64 swz); later P (LD72)
  __shared__ bf16_t ls_pkr[64 * 196];  // pk staged (192x64 swz); later R (LD196)
  __shared__ bf16_t ls_k[64 * 64];     // swizzled
  __shared__ bf16_t ls_vt[64 * 72];    // [d][s], LD72

  const int tid = threadIdx.x, w = tid >> 6, lane = tid & 63;
  const int lanelo = lane & 15, quad = lane >> 4;
  const int wbase = tid & ~63;
  const int t0 = blockIdx.x * 64;
  const int bh = blockIdx.y, bb = bh >> 2, h = bh & 3;
  const int z = blockIdx.z;
  const size_t rowbase = (size_t)bb * T_;
  const int jb = t0 - 128 * z + 873;

  // ---- phase 0: stage q, pk, K(tile0) async; V(tile0) manual; masks ----
#pragma unroll
  for (int rr = 0; rr < 2; ++rr) {
    int chunk = rr * 256 + tid;
    int r = chunk >> 3, c8 = chunk & 7;
    int lg = c8 ^ (r & 7);
    async_cp16(qkv + (rowbase + t0 + r) * 768 + h * 64 + lg * 8,
               ls_qp + (size_t)(rr * 256 + wbase) * 8);
  }
#pragma unroll
  for (int rr = 0; rr < 6; ++rr) {
    int chunk = rr * 256 + tid;
    int r = chunk >> 3, c8 = chunk & 7;
    int lg = c8 ^ (r & 7);
    async_cp16(pkn + (size_t)(jb + r) * DK + lg * 8,
               ls_pkr + (size_t)(rr * 256 + wbase) * 8);
  }
  const int s0_0 = 128 * z;
#pragma unroll
  for (int rr = 0; rr < 2; ++rr) {
    int chunk = rr * 256 + tid;
    int r = chunk >> 3, c8 = chunk & 7;
    int lg = c8 ^ (r & 7);
    async_cp16(qkv + (rowbase + s0_0 + r) * 768 + 256 + h * 64 + lg * 8,
               ls_k + (size_t)(rr * 256 + wbase) * 8);
  }
#pragma unroll
  for (int c = tid; c < 64 * 8; c += 256) {
    int r = c & 63, d0 = (c >> 6) * 8;
    bf16x8 vv = *(const bf16x8*)(qkv + (rowbase + s0_0 + r) * 768 + 512 + h * 64 + d0);
#pragma unroll
    for (int i = 0; i < 8; ++i) ls_vt[(d0 + i) * 72 + r] = vv[i];
  }
  int mk[2][4];
#pragma unroll
  for (int stl = 0; stl < 2; ++stl)
#pragma unroll
    for (int nf = 0; nf < 4; ++nf)
      mk[stl][nf] = masks[bb * T_ + 128 * z + 64 * stl + nf * 16 + lanelo];
  __syncthreads();  // barrier 1

  // ---- R GEMM over staged pk (hides tile-0 staging latency) ----
  bf16x8 qf[2];
#pragma unroll
  for (int kk = 0; kk < 2; ++kk) {
    int r = w * 16 + lanelo;
    qf[kk] = *(const bf16x8*)(ls_qp + (size_t)(r * 8 + ((kk * 4 + quad) ^ (r & 7))) * 8);
  }
  f32x4 racc[12] = {};
#pragma unroll
  for (int kk = 0; kk < 2; ++kk)
#pragma unroll
    for (int nf = 0; nf < 12; ++nf) {
      int r = nf * 16 + lanelo;
      bf16x8 bj = *(const bf16x8*)(ls_pkr + (size_t)(r * 8 + ((kk * 4 + quad) ^ (r & 7))) * 8);
      racc[nf] = mfma16(qf[kk], bj, racc[nf]);
    }
  __syncthreads();  // barrier 2: pk reads complete -> ls_pkr reusable as R
#pragma unroll
  for (int nf = 0; nf < 12; ++nf)
#pragma unroll
    for (int reg = 0; reg < 4; ++reg)
      ls_pkr[(w * 16 + quad * 4 + reg) * 196 + nf * 16 + lanelo] =
          (bf16_t)racc[nf][reg];
  // R rows + later gathers are wave-own 16-row bands: same-wave DS order, no
  // barrier needed.

  f32x4 o_acc[4] = {};
  float m_run[4], l_run[4];
#pragma unroll
  for (int i = 0; i < 4; ++i) { m_run[i] = -__builtin_inff(); l_run[i] = 0.f; }

  for (int stl = 0; stl < 2; ++stl) {
    const int s0 = 128 * z + 64 * stl;
    if (stl) {
      __syncthreads();  // barrier 3: all waves done with tile-0 K/V
#pragma unroll
      for (int rr = 0; rr < 2; ++rr) {
        int chunk = rr * 256 + tid;
        int r = chunk >> 3, c8 = chunk & 7;
        int lg = c8 ^ (r & 7);
        async_cp16(qkv + (rowbase + s0 + r) * 768 + 256 + h * 64 + lg * 8,
                   ls_k + (size_t)(rr * 256 + wbase) * 8);
      }
#pragma unroll
      for (int c = tid; c < 64 * 8; c += 256) {
        int r = c & 63, d0 = (c >> 6) * 8;
        bf16x8 vv = *(const bf16x8*)(qkv + (rowbase + s0 + r) * 768 + 512 + h * 64 + d0);
#pragma unroll
        for (int i = 0; i < 8; ++i) ls_vt[(d0 + i) * 72 + r] = vv[i];
      }
      __syncthreads();  // barrier 4
    }

    // S GEMM
    f32x4 sacc[4] = {};
#pragma unroll
    for (int kk = 0; kk < 2; ++kk)
#pragma unroll
      for (int nf = 0; nf < 4; ++nf) {
        int r = nf * 16 + lanelo;
        bf16x8 bk = *(const bf16x8*)(ls_k + (size_t)(r * 8 + ((kk * 4 + quad) ^ (r & 7))) * 8);
        sacc[nf] = mfma16(qf[kk], bk, sacc[nf]);
      }
    // rel-bias gather from LDS R (wave-own rows)
    float sv[4][4];
#pragma unroll
    for (int nf = 0; nf < 4; ++nf) {
      const int scol = nf * 16 + lanelo;
#pragma unroll
      for (int reg = 0; reg < 4; ++reg) {
        const int trow = w * 16 + quad * 4 + reg;
        const float bt = (float)ls_pkr[trow * 196 + (trow - scol - 64 * stl + 127)];
        sv[nf][reg] = mk[stl][nf] ? (sacc[nf][reg] + bt) * 0.125f : -3.4028235e38f;
      }
    }
    // online softmax
    float alpha[4];
#pragma unroll
    for (int reg = 0; reg < 4; ++reg) {
      float bm = fmaxf(fmaxf(sv[0][reg], sv[1][reg]), fmaxf(sv[2][reg], sv[3][reg]));
#pragma unroll
      for (int o = 1; o < 16; o <<= 1) bm = fmaxf(bm, __shfl_xor(bm, o));
      const float mn = fmaxf(m_run[reg], bm);
      alpha[reg] = __expf(m_run[reg] - mn);
      m_run[reg] = mn;
      float rsum = 0.f;
#pragma unroll
      for (int nf = 0; nf < 4; ++nf) {
        float p = __expf(sv[nf][reg] - mn) * (mk[stl][nf] ? 1.f : 0.f);
        sv[nf][reg] = p;
        rsum += p;
      }
#pragma unroll
      for (int o = 1; o < 16; o <<= 1) rsum += __shfl_xor(rsum, o);
      l_run[reg] = l_run[reg] * alpha[reg] + rsum;
    }
    // P write (wave-own rows) + PV
#pragma unroll
    for (int nf = 0; nf < 4; ++nf)
#pragma unroll
      for (int reg = 0; reg < 4; ++reg) {
        o_acc[nf][reg] *= alpha[reg];
        ls_qp[(w * 16 + quad * 4 + reg) * 72 + nf * 16 + lanelo] = (bf16_t)sv[nf][reg];
      }
#pragma unroll
    for (int kk = 0; kk < 2; ++kk) {
      bf16x8 ap = *(const bf16x8*)&ls_qp[(w * 16 + lanelo) * 72 + kk * 32 + quad * 8];
#pragma unroll
      for (int nf = 0; nf < 4; ++nf) {
        bf16x8 bv = *(const bf16x8*)&ls_vt[(nf * 16 + lanelo) * 72 + kk * 32 + quad * 8];
        o_acc[nf] = mfma16(ap, bv, o_acc[nf]);
      }
    }
  }

  // write split partials (bf16 O + f32 m,l)
#pragma unroll
  for (int reg = 0; reg < 4; ++reg) {
    const int trow = w * 16 + quad * 4 + reg;
    const size_t prow = ((size_t)z * NBH + bh) * T_ + t0 + trow;
#pragma unroll
    for (int nf = 0; nf < 4; ++nf)
      Opart[prow * 64 + nf * 16 + lanelo] = (bf16_t)o_acc[nf][reg];
    if (lanelo == 0) { mpart[prow] = m_run[reg]; lpart[prow] = l_run[reg]; }
  }
}

// ---------------------------------------------------------------------------
// host
// ---------------------------------------------------------------------------
extern "C" void kernel_launch(void* const* d_in, const int* in_sizes, int n_in,
                              void* d_out, int out_size, void* d_ws, size_t ws_size,
                              hipStream_t stream) {
  const float* xs       = (const float*)d_in[0];
  const int*   masks    = (const int*)d_in[1];
  const float* emb_w    = (const float*)d_in[2];
  const float* emb_b    = (const float*)d_in[3];
  const float* emb_g    = (const float*)d_in[4];
  const float* emb_beta = (const float*)d_in[5];
  const float* pe_k     = (const float*)d_in[6];
  const float* Wq       = (const float*)d_in[7];
  const float* bq       = (const float*)d_in[8];
  const float* Wk       = (const float*)d_in[9];
  const float* bk       = (const float*)d_in[10];
  const float* Wv       = (const float*)d_in[11];
  const float* bv       = (const float*)d_in[12];
  const float* Wo       = (const float*)d_in[13];
  const float* bo       = (const float*)d_in[14];
  const float* ln1_g    = (const float*)d_in[15];
  const float* ln1_b    = (const float*)d_in[16];
  const float* ln2_g    = (const float*)d_in[17];
  const float* ln2_b    = (const float*)d_in[18];
  const float* lnk_g    = (const float*)d_in[19];
  const float* lnk_b    = (const float*)d_in[20];
  const float* W1       = (const float*)d_in[21];
  const float* b1       = (const float*)d_in[22];
  const float* W2       = (const float*)d_in[23];
  const float* b2       = (const float*)d_in[24];
  const float* after_g  = (const float*)d_in[25];
  const float* after_b  = (const float*)d_in[26];

  char* ws = (char*)d_ws;
  size_t off = 0;
  auto take = [&](size_t bytes) -> void* {
    void* p = ws + off;
    off += (bytes + 255) & ~(size_t)255;
    return p;
  };
  bf16_t* ewb  = (bf16_t*)take((size_t)D_ * KPAD * 2);
  bf16_t* wcat = (bf16_t*)take((size_t)L_ * 768 * D_ * 2);
  float*  bcat = (float*) take((size_t)L_ * 768 * 4);
  bf16_t* wob  = (bf16_t*)take((size_t)L_ * D_ * D_ * 2);
  bf16_t* w1b  = (bf16_t*)take((size_t)L_ * FF_ * D_ * 2);
  bf16_t* w2b  = (bf16_t*)take((size_t)L_ * D_ * FF_ * 2);
  bf16_t* pknb = (bf16_t*)take((size_t)L_ * PKROWS * DK * 2);
  float*  x    = (float*) take((size_t)NROW * D_ * 4);
  bf16_t* y    = (bf16_t*)take((size_t)NROW * D_ * 2);
  bf16_t* qkv  = (bf16_t*)take((size_t)NROW * 768 * 2);
  bf16_t* hbuf = (bf16_t*)take((size_t)NROW * FF_ * 2);
  bf16_t* Opart = (bf16_t*)take((size_t)NSA * NBH * T_ * 64 * 2);
  float*  mpart = (float*)take((size_t)NSA * NBH * T_ * 4);
  float*  lpart = (float*)take((size_t)NSA * NBH * T_ * 4);
  float*  gpart = (float*)take((size_t)4 * NROW * D_ * 4);
  bf16_t* xsb  = hbuf;  // xs bf16 only needed before first FF1
  const size_t ZS = (size_t)NROW * D_;

  // prep
  cvt_pad_row<<<NROW, 256, 0, stream>>>(xs, xsb, IDIM, KPAD);
  cvt_pad_row<<<D_, 256, 0, stream>>>(emb_w, ewb, IDIM, KPAD);
  prep_all<<<4096, 256, 0, stream>>>(Wq, Wk, Wv, Wo, W1, W2, bq, bk, bv,
                                     wcat, wob, w1b, w2b, bcat);
  pkn_ln<<<(L_ * PKROWS) / 4, 256, 0, stream>>>(pe_k, lnk_g, lnk_b, pknb);

  // embed: 128x128 split-K=4 -> combine (LN+relu, then ln1 of layer 0)
  gemm_bf16<128, 128, 4, 2><<<dim3(NROW / 128, D_ / 128, 4), 256, 0, stream>>>(
      xsb, KPAD, ewb, KPAD, nullptr, gpart, D_, KPAD, ZS);
  embed_combine<<<NROW / 4, 256, 0, stream>>>(gpart, emb_b, emb_g, emb_beta,
                                              ln1_g, ln1_b, x, y);

  for (int l = 0; l < L_; ++l) {
    // QKV projection
    gemm_bf16<64, 128, 1, 3><<<dim3(NROW / 64, 768 / 128), 256, 0, stream>>>(
        y, D_, wcat + (size_t)l * 768 * D_, D_, bcat + l * 768, qkv, 768, D_, 0);
    // fused flash attention (rel-bias in LDS), s-split 4
    attn_fused<<<dim3(T_ / 64, NBH, NSA), 256, 0, stream>>>(
        qkv, pknb + (size_t)l * PKROWS * DK, masks, Opart, mpart, lpart);
    // Wo GEMM with inline split-combine; split-K=2 partials
    wo_gemm<<<dim3(NROW / 64, D_ / 128, 2), 256, 0, stream>>>(
        Opart, mpart, lpart, wob + (size_t)l * D_ * D_, gpart, ZS);
    add_combine_ln<2, true><<<NROW / 4, 256, 0, stream>>>(
        gpart, bo + l * D_, x, ln2_g + l * D_, ln2_b + l * D_, y);
    // FF1
    gemm_bf16<128, 128, 2, 2><<<dim3(NROW / 128, FF_ / 128), 256, 0, stream>>>(
        y, D_, w1b + (size_t)l * FF_ * D_, D_, b1 + l * FF_, hbuf, FF_, D_, 0);
    // FF2: 128x128 split-K=4
    gemm_bf16<128, 128, 4, 2><<<dim3(NROW / 128, D_ / 128, 4), 256, 0, stream>>>(
        hbuf, FF_, w2b + (size_t)l * D_ * FF_, FF_, nullptr, gpart, D_, FF_, ZS);
    if (l < L_ - 1) {
      add_combine_ln<4, true><<<NROW / 4, 256, 0, stream>>>(
          gpart, b2 + l * D_, x, ln1_g + (l + 1) * D_, ln1_b + (l + 1) * D_, y);
    } else {
      add_combine_ln<4, false><<<NROW / 4, 256, 0, stream>>>(
          gpart, b2 + l * D_, x, nullptr, nullptr, nullptr);
    }
  }
  ln_rows_f32<<<NROW / 4, 256, 0, stream>>>(x, after_g, after_b, (float*)d_out);
}